// Round 11
// baseline (31.195 us; speedup 1.0000x reference)
//
#include <hip/hip_runtime.h>
#include <hip/hip_fp16.h>

#define NPIX (384*384)        // 147456
#define NSAMP 32
#define ROWS 64               // 32 region rows + 32 affinity rows
#define BINS 1024             // exponent(8) + 3 mantissa bits; l in [0,1) -> bin <= 1015
#define REPL 2                // LDS histogram replication
#define THREADS 256
#define BLKROW 36
#define EPB (NPIX / BLKROW)   // 4096 elements per block
#define NIT (EPB / (THREADS * 4))   // 4 float4-iterations per thread
#define FXSCALE 268435456.0f  // 2^28 fixed-point scale for packed LDS bin sums
#define FXINV   3.7252902984619141e-9
#define MASK46  ((1ULL << 46) - 1)
// LDS packed bin (exact): (count << 46) | fixed_point_sum.
//   per block: count <= 4096; sum < 4096 * 2^28 = 2^40 < 2^46.
// Global partial bin (compact): u32 = (count << 16) | f16bits(sum).
//   count <= 4096 < 2^16; sum <= 4096 < f16 max; f16 rel err ~5e-4 -> ~3e-4
//   on the final output (threshold 2.58e-2).

// workspace layout (no zero-init needed anywhere):
//   part [ROWS][BLKROW][BINS] u32   partial histograms (9.4 MB, plain stores)
//   pstat[ROWS][BLKROW]       u64   per-block (n_pos<<32 | f32bits(pos_sum))
#define PART_U32   ((size_t)ROWS * BLKROW * BINS)
#define PSTAT_OFF  (PART_U32 * 4)

// Per (row, chunk) block: loss for 4096 pixels -> 1024-bin packed (cnt,sum)
// histogram in LDS (2-way replicated u64), flushed as compact u32
// (cnt<<16|f16 sum) with plain coalesced stores to a private slot.
// ZERO global atomics (R9 lesson: contended device-scope atomics cost
// ~17us while invisible in SQ counters).
__global__ __launch_bounds__(THREADS) void k_hist(
    const float* __restrict__ gt_r, const float* __restrict__ gt_a,
    const float* __restrict__ pr_r, const float* __restrict__ pr_a,
    const float* __restrict__ conf,
    unsigned int* __restrict__ part,
    unsigned long long* __restrict__ pstat,
    float* __restrict__ out)
{
    __shared__ unsigned long long s_hist[BINS * REPL];   // 16 KB
    __shared__ unsigned int s_pc;
    __shared__ float s_ps;
    const int tid = threadIdx.x;
    const int row = blockIdx.y;
    const int chunk = blockIdx.x;
    const int samp = row & (NSAMP - 1);
    const float* gt = (row < NSAMP) ? gt_r : gt_a;
    const float* pr = (row < NSAMP) ? pr_r : pr_a;
    const unsigned copy = tid & (REPL - 1);

    // zero d_out for k_sel's atomicAdd (safe: consumed only after this kernel)
    if (row == 0 && chunk == 0 && tid == 0) out[0] = 0.f;

    for (int i = tid; i < BINS * REPL; i += THREADS) s_hist[i] = 0ULL;
    if (tid == 0) { s_pc = 0u; s_ps = 0.f; }
    __syncthreads();

    // issue all 12 vector loads up front for memory-level parallelism
    size_t base = (size_t)samp * NPIX + (size_t)chunk * EPB + (size_t)tid * 4;
    float4 g[NIT], p[NIT], c[NIT];
    #pragma unroll
    for (int it = 0; it < NIT; ++it) {
        size_t idx = base + (size_t)it * THREADS * 4;
        g[it] = *(const float4*)(gt + idx);
        p[it] = *(const float4*)(pr + idx);
        c[it] = *(const float4*)(conf + idx);
    }

    unsigned pc = 0; float ps = 0.f;
    #pragma unroll
    for (int it = 0; it < NIT; ++it) {
        float gv[4] = {g[it].x, g[it].y, g[it].z, g[it].w};
        float pv[4] = {p[it].x, p[it].y, p[it].z, p[it].w};
        float cv[4] = {c[it].x, c[it].y, c[it].z, c[it].w};
        #pragma unroll
        for (int j = 0; j < 4; ++j) {
            float d = pv[j] - gv[j];
            float l = d * d * cv[j];
            if (gv[j] >= 0.1f) { pc++; ps += l; }
            else {
                unsigned bin = __float_as_uint(l) >> 20;   // l < 1 -> bin <= 1015
                unsigned long long pk =
                    (1ULL << 46) | (unsigned long long)(unsigned)(l * FXSCALE);
                atomicAdd(&s_hist[(bin << 1) | copy], pk);
            }
        }
    }

    // wave-reduce positive stats -> LDS (no global atomics)
    for (int off = 32; off; off >>= 1) {
        pc += __shfl_down(pc, off);
        ps += __shfl_down(ps, off);
    }
    if ((tid & 63) == 0) { atomicAdd(&s_pc, pc); atomicAdd(&s_ps, ps); }
    __syncthreads();

    // private flush: plain coalesced u32 stores, zero contention, no zero-init
    unsigned int* dst = part + ((size_t)row * BLKROW + chunk) * BINS;
    for (int i = tid; i < BINS; i += THREADS) {
        unsigned long long v = s_hist[i << 1] + s_hist[(i << 1) | 1];
        unsigned cnt = (unsigned)(v >> 46);
        float sum = (float)((double)(v & MASK46) * FXINV);
        dst[i] = (cnt << 16) |
                 (unsigned)__half_as_ushort(__float2half_rn(sum));
    }

    if (tid == 0)
        pstat[(size_t)row * BLKROW + chunk] =
            ((unsigned long long)s_pc << 32) | (unsigned long long)__float_as_uint(s_ps);
}

// Per row: reduce 36 (n_pos,pos_sum) pairs, sum 36 compact partial
// histograms (one uint4 = 4 bins per chunk-load), parallel descending
// suffix-scan over (count, sum); boundary bin's partial take approximated
// by the bin's true mean (~1e-3 output error).
__global__ __launch_bounds__(THREADS) void k_sel(
    const unsigned int* __restrict__ part,
    const unsigned long long* __restrict__ pstat,
    float* __restrict__ out)
{
    const int row = blockIdx.x;           // 0..63
    const int tid = threadIdx.x;
    __shared__ unsigned s_npos; __shared__ float s_psum;
    __shared__ unsigned wtc[4]; __shared__ float wts[4];

    // wave 0 reduces the 36 per-block stat pairs
    if (tid < 64) {
        unsigned pc = 0; float ps = 0.f;
        if (tid < BLKROW) {
            unsigned long long v = pstat[(size_t)row * BLKROW + tid];
            pc = (unsigned)(v >> 32);
            ps = __uint_as_float((unsigned)(v & 0xFFFFFFFFu));
        }
        for (int off = 32; off; off >>= 1) {
            pc += __shfl_down(pc, off);
            ps += __shfl_down(ps, off);
        }
        if (tid == 0) { s_npos = pc; s_psum = ps; }
    }

    // accumulate my 4 descending-rank bins over the 36 chunk partials.
    // rank r = tid*4+j -> bin = 1023 - r; the thread's 4 bins are one
    // 16B-aligned uint4 per chunk.
    const unsigned int* base = part + (size_t)row * BLKROW * BINS;
    unsigned c[4] = {0, 0, 0, 0};
    float    s[4] = {0.f, 0.f, 0.f, 0.f};
    for (int ch = 0; ch < BLKROW; ++ch) {
        uint4 q = *(const uint4*)(base + (size_t)ch * BINS + (BINS - 4 - tid * 4));
        unsigned v[4] = {q.w, q.z, q.y, q.x};    // descending-rank order
        #pragma unroll
        for (int j = 0; j < 4; ++j) {
            c[j] += v[j] >> 16;
            s[j] += __half2float(__ushort_as_half((unsigned short)(v[j] & 0xFFFFu)));
        }
    }
    __syncthreads();

    const unsigned n_pos = s_npos;
    const float pos_sum = s_psum;
    const unsigned n_neg = NPIX - n_pos;
    const float pos_part = (n_pos > 0u) ? pos_sum / (float)n_pos : 0.f;
    if (n_neg == 0u) {
        if (tid == 0) atomicAdd(out, (pos_part - 1.f) / (float)NSAMP); // sentinel -1
        return;
    }
    unsigned k;
    if (n_pos > 0u) {
        k = 3u * n_pos;
        if (k > n_neg) k = n_neg;
        if (k < 1u) k = 1u;
    } else {
        k = 500u;   // fallback: top-500 (all pixels are negatives when n_pos==0)
    }

    unsigned tc = 0; float ts = 0.f;
    #pragma unroll
    for (int j = 0; j < 4; ++j) { tc += c[j]; ts += s[j]; }

    unsigned lane = tid & 63, w = tid >> 6;
    unsigned ic = tc; float is = ts;
    #pragma unroll
    for (int off = 1; off < 64; off <<= 1) {
        unsigned uc = __shfl_up(ic, off);
        float    us = __shfl_up(is, off);
        if (lane >= off) { ic += uc; is += us; }
    }
    if (lane == 63) { wtc[w] = ic; wts[w] = is; }
    __syncthreads();
    unsigned woc = 0; float wos = 0.f;
    for (unsigned i = 0; i < w; ++i) { woc += wtc[i]; wos += wts[i]; }
    unsigned before_c = woc + ic - tc;   // count strictly above my first rank
    float    before_s = wos + is - ts;

    #pragma unroll
    for (int j = 0; j < 4; ++j) {
        if (before_c < k && before_c + c[j] >= k) {
            unsigned kpp = k - before_c;             // 1 <= kpp <= c[j]
            float mean = s[j] / (float)c[j];
            float topk = before_s + (float)kpp * mean;
            atomicAdd(out, (pos_part + topk / (float)k) / (float)NSAMP);
        }
        before_c += c[j]; before_s += s[j];
    }
}

extern "C" void kernel_launch(void* const* d_in, const int* in_sizes, int n_in,
                              void* d_out, int out_size, void* d_ws, size_t ws_size,
                              hipStream_t stream)
{
    (void)in_sizes; (void)n_in; (void)out_size; (void)ws_size;
    const float* gt_r = (const float*)d_in[0];
    const float* gt_a = (const float*)d_in[1];
    const float* pr_r = (const float*)d_in[2];
    const float* pr_a = (const float*)d_in[3];
    const float* conf = (const float*)d_in[4];

    char* ws = (char*)d_ws;
    unsigned int*       part  = (unsigned int*)ws;
    unsigned long long* pstat = (unsigned long long*)(ws + PSTAT_OFF);

    dim3 gridH(BLKROW, ROWS);
    k_hist<<<gridH, THREADS, 0, stream>>>(gt_r, gt_a, pr_r, pr_a, conf,
                                          part, pstat, (float*)d_out);
    k_sel<<<ROWS, THREADS, 0, stream>>>(part, pstat, (float*)d_out);
}

// Round 12
// 28.111 us; speedup vs baseline: 1.1097x; 1.1097x over previous
//
#include <hip/hip_runtime.h>
#include <hip/hip_fp16.h>

#define NPIX (384*384)        // 147456
#define NSAMP 32
#define ROWS 64               // 32 region rows + 32 affinity rows
#define BINS 1024             // exponent(8) + 3 mantissa bits; l in [0,1) -> bin <= 1015
#define REPL 2                // LDS histogram replication
#define THREADS 256
#define BLKROW 32             // 64 x 32 = 2048 blocks = exactly 8/CU resident
#define EPB (NPIX / BLKROW)   // 4608 elements per block = 4 full + 1 half iter
#define SELTHREADS 1024
#define FXSCALE 268435456.0f  // 2^28 fixed-point scale for packed LDS bin sums
#define FXINV   3.7252902984619141e-9
#define MASK46  ((1ULL << 46) - 1)
// LDS packed bin (exact): (count << 46) | fixed_point_sum.
//   per block: count <= 4608; sum < 4608 * 2^28 < 2^41 < 2^46.
// Global partial bin (compact): u32 = (count << 16) | f16bits(sum).
//   count <= 4608 < 2^16; sum <= 4608 < f16 max; f16 rel err ~5e-4.

// workspace layout (no zero-init needed anywhere):
//   part [ROWS][BLKROW][BINS] u32   partial histograms (8 MB, plain stores)
//   pstat[ROWS][BLKROW]       u64   per-block (n_pos<<32 | f32bits(pos_sum))
#define PART_U32   ((size_t)ROWS * BLKROW * BINS)
#define PSTAT_OFF  (PART_U32 * 4)

// Per (row, chunk) block: loss for 4608 pixels -> 1024-bin packed (cnt,sum)
// histogram in LDS (2-way replicated u64), flushed as compact u32 with plain
// coalesced stores to a private slot. ZERO global atomics (R9 lesson:
// contended device-scope atomics cost ~17us, invisible in SQ counters).
__global__ __launch_bounds__(THREADS, 8) void k_hist(
    const float* __restrict__ gt_r, const float* __restrict__ gt_a,
    const float* __restrict__ pr_r, const float* __restrict__ pr_a,
    const float* __restrict__ conf,
    unsigned int* __restrict__ part,
    unsigned long long* __restrict__ pstat,
    float* __restrict__ out)
{
    __shared__ unsigned long long s_hist[BINS * REPL];   // 16 KB
    __shared__ unsigned int s_pc;
    __shared__ float s_ps;
    const int tid = threadIdx.x;
    const int row = blockIdx.y;
    const int chunk = blockIdx.x;
    const int samp = row & (NSAMP - 1);
    const float* gt = (row < NSAMP) ? gt_r : gt_a;
    const float* pr = (row < NSAMP) ? pr_r : pr_a;
    const unsigned copy = tid & (REPL - 1);

    // zero d_out for k_sel's atomicAdd (safe: consumed only after this kernel)
    if (row == 0 && chunk == 0 && tid == 0) out[0] = 0.f;

    for (int i = tid; i < BINS * REPL; i += THREADS) s_hist[i] = 0ULL;
    if (tid == 0) { s_pc = 0u; s_ps = 0.f; }
    __syncthreads();

    const size_t base0 = (size_t)samp * NPIX + (size_t)chunk * EPB;
    unsigned pc = 0; float ps = 0.f;

    #pragma unroll
    for (int it = 0; it < 5; ++it) {            // it==4 is the half-iteration
        if (it == 4 && tid >= 128) break;
        size_t idx = base0 + (size_t)it * THREADS * 4 + (size_t)tid * 4;
        float4 g = *(const float4*)(gt + idx);
        float4 p = *(const float4*)(pr + idx);
        float4 c = *(const float4*)(conf + idx);
        float gv[4] = {g.x, g.y, g.z, g.w};
        float pv[4] = {p.x, p.y, p.z, p.w};
        float cv[4] = {c.x, c.y, c.z, c.w};
        #pragma unroll
        for (int j = 0; j < 4; ++j) {
            float d = pv[j] - gv[j];
            float l = d * d * cv[j];
            if (gv[j] >= 0.1f) { pc++; ps += l; }
            else {
                unsigned bin = __float_as_uint(l) >> 20;   // l < 1 -> bin <= 1015
                unsigned long long pk =
                    (1ULL << 46) | (unsigned long long)(unsigned)(l * FXSCALE);
                atomicAdd(&s_hist[(bin << 1) | copy], pk);
            }
        }
    }

    // wave-reduce positive stats -> LDS (no global atomics)
    for (int off = 32; off; off >>= 1) {
        pc += __shfl_down(pc, off);
        ps += __shfl_down(ps, off);
    }
    if ((tid & 63) == 0) { atomicAdd(&s_pc, pc); atomicAdd(&s_ps, ps); }
    __syncthreads();

    // private flush: plain coalesced u32 stores, zero contention, no zero-init
    unsigned int* dst = part + ((size_t)row * BLKROW + chunk) * BINS;
    for (int i = tid; i < BINS; i += THREADS) {
        unsigned long long v = s_hist[i << 1] + s_hist[(i << 1) | 1];
        unsigned cnt = (unsigned)(v >> 46);
        float sum = (float)((double)(v & MASK46) * FXINV);
        dst[i] = (cnt << 16) |
                 (unsigned)__half_as_ushort(__float2half_rn(sum));
    }

    if (tid == 0)
        pstat[(size_t)row * BLKROW + chunk] =
            ((unsigned long long)s_pc << 32) | (unsigned long long)__float_as_uint(s_ps);
}

// Per row, 1024 threads (1 bin/thread, 16 waves): reduce 32 stat pairs,
// sum 32 compact partials, two-level inclusive scan in descending-bin order,
// boundary bin's partial take approximated by the bin's true mean.
__global__ __launch_bounds__(SELTHREADS) void k_sel(
    const unsigned int* __restrict__ part,
    const unsigned long long* __restrict__ pstat,
    float* __restrict__ out)
{
    const int row = blockIdx.x;           // 0..63
    const int tid = threadIdx.x;          // 0..1023
    __shared__ unsigned s_npos; __shared__ float s_psum;
    __shared__ unsigned wtc[16]; __shared__ float wts[16];

    // wave 0 reduces the 32 per-block stat pairs
    if (tid < 64) {
        unsigned pc = 0; float ps = 0.f;
        if (tid < BLKROW) {
            unsigned long long v = pstat[(size_t)row * BLKROW + tid];
            pc = (unsigned)(v >> 32);
            ps = __uint_as_float((unsigned)(v & 0xFFFFFFFFu));
        }
        for (int off = 32; off; off >>= 1) {
            pc += __shfl_down(pc, off);
            ps += __shfl_down(ps, off);
        }
        if (tid == 0) { s_npos = pc; s_psum = ps; }
    }

    // my bin: descending rank r = tid -> bin = 1023 - tid
    const int bin = BINS - 1 - tid;
    const unsigned int* base = part + (size_t)row * BLKROW * BINS + bin;
    unsigned c = 0; float s = 0.f;
    #pragma unroll
    for (int ch = 0; ch < BLKROW; ++ch) {
        unsigned v = base[(size_t)ch * BINS];
        c += v >> 16;
        s += __half2float(__ushort_as_half((unsigned short)(v & 0xFFFFu)));
    }

    // two-level inclusive scan over (c, s) in rank order
    unsigned lane = tid & 63, w = tid >> 6;   // 16 waves
    unsigned ic = c; float is = s;
    #pragma unroll
    for (int off = 1; off < 64; off <<= 1) {
        unsigned uc = __shfl_up(ic, off);
        float    us = __shfl_up(is, off);
        if (lane >= off) { ic += uc; is += us; }
    }
    if (lane == 63) { wtc[w] = ic; wts[w] = is; }
    __syncthreads();
    unsigned woc = 0; float wos = 0.f;
    for (unsigned i = 0; i < w; ++i) { woc += wtc[i]; wos += wts[i]; }
    const unsigned before_c = woc + ic - c;   // count strictly above my bin
    const float    before_s = wos + is - s;

    const unsigned n_pos = s_npos;
    const float pos_sum = s_psum;
    const unsigned n_neg = NPIX - n_pos;
    const float pos_part = (n_pos > 0u) ? pos_sum / (float)n_pos : 0.f;
    if (n_neg == 0u) {
        if (tid == 0) atomicAdd(out, (pos_part - 1.f) / (float)NSAMP); // sentinel -1
        return;
    }
    unsigned k;
    if (n_pos > 0u) {
        k = 3u * n_pos;
        if (k > n_neg) k = n_neg;
        if (k < 1u) k = 1u;
    } else {
        k = 500u;   // fallback: top-500 (all pixels are negatives when n_pos==0)
    }

    if (before_c < k && before_c + c >= k) {
        unsigned kpp = k - before_c;             // 1 <= kpp <= c
        float mean = s / (float)c;
        float topk = before_s + (float)kpp * mean;
        atomicAdd(out, (pos_part + topk / (float)k) / (float)NSAMP);
    }
}

extern "C" void kernel_launch(void* const* d_in, const int* in_sizes, int n_in,
                              void* d_out, int out_size, void* d_ws, size_t ws_size,
                              hipStream_t stream)
{
    (void)in_sizes; (void)n_in; (void)out_size; (void)ws_size;
    const float* gt_r = (const float*)d_in[0];
    const float* gt_a = (const float*)d_in[1];
    const float* pr_r = (const float*)d_in[2];
    const float* pr_a = (const float*)d_in[3];
    const float* conf = (const float*)d_in[4];

    char* ws = (char*)d_ws;
    unsigned int*       part  = (unsigned int*)ws;
    unsigned long long* pstat = (unsigned long long*)(ws + PSTAT_OFF);

    dim3 gridH(BLKROW, ROWS);
    k_hist<<<gridH, THREADS, 0, stream>>>(gt_r, gt_a, pr_r, pr_a, conf,
                                          part, pstat, (float*)d_out);
    k_sel<<<ROWS, SELTHREADS, 0, stream>>>(part, pstat, (float*)d_out);
}

// Round 13
// 25.703 us; speedup vs baseline: 1.2137x; 1.0937x over previous
//
#include <hip/hip_runtime.h>

#define NPIX (384*384)        // 147456
#define NSAMP 32
#define ROWS 64               // 32 region rows + 32 affinity rows
#define BINS2 2048            // exponent(8) + 4 mantissa bits; l in [0,1) -> bin <= 2031
#define REPL 2                // LDS histogram replication
#define THREADS 256
#define BLKROW 32             // 64 x 32 = 2048 blocks = exactly 8/CU resident
#define EPB (NPIX / BLKROW)   // 4608 elements per block = 4 full + 1 half iter
#define SELTHREADS 1024

// workspace layout (no zero-init needed anywhere):
//   part [ROWS][BLKROW][BINS2/2] u32  (two u16 counts packed; 8 MB, plain stores)
//   pstat[ROWS][BLKROW]          u64  per-block (n_pos<<32 | f32bits(pos_sum))
// per-block count <= 4608 < 2^16 fits u16.
#define PART_U32   ((size_t)ROWS * BLKROW * (BINS2 / 2))
#define PSTAT_OFF  (PART_U32 * 4)

// Per (row, chunk) block: loss for 4608 pixels -> 2048-bin count histogram in
// LDS (2-way replicated u32 — u32 RMW touches 1 bank vs u64's 2), flushed as
// packed u16-pair u32 stores to a private slot. ZERO global atomics
// (R9 lesson: contended device-scope atomics cost ~17us, invisible in SQ).
__global__ __launch_bounds__(THREADS, 8) void k_hist(
    const float* __restrict__ gt_r, const float* __restrict__ gt_a,
    const float* __restrict__ pr_r, const float* __restrict__ pr_a,
    const float* __restrict__ conf,
    unsigned int* __restrict__ part,
    unsigned long long* __restrict__ pstat,
    float* __restrict__ out)
{
    __shared__ unsigned int s_cnt[BINS2 * REPL];   // 16 KB
    __shared__ unsigned int s_pc;
    __shared__ float s_ps;
    const int tid = threadIdx.x;
    const int row = blockIdx.y;
    const int chunk = blockIdx.x;
    const int samp = row & (NSAMP - 1);
    const float* gt = (row < NSAMP) ? gt_r : gt_a;
    const float* pr = (row < NSAMP) ? pr_r : pr_a;
    const unsigned copy = tid & (REPL - 1);

    // zero d_out for k_sel's atomicAdd (safe: consumed only after this kernel)
    if (row == 0 && chunk == 0 && tid == 0) out[0] = 0.f;

    for (int i = tid; i < BINS2 * REPL; i += THREADS) s_cnt[i] = 0u;
    if (tid == 0) { s_pc = 0u; s_ps = 0.f; }
    __syncthreads();

    const size_t base0 = (size_t)samp * NPIX + (size_t)chunk * EPB;
    unsigned pc = 0; float ps = 0.f;

    #pragma unroll
    for (int it = 0; it < 5; ++it) {            // it==4 is the half-iteration
        if (it == 4 && tid >= 128) break;
        size_t idx = base0 + (size_t)it * THREADS * 4 + (size_t)tid * 4;
        float4 g = *(const float4*)(gt + idx);
        float4 p = *(const float4*)(pr + idx);
        float4 c = *(const float4*)(conf + idx);
        float gv[4] = {g.x, g.y, g.z, g.w};
        float pv[4] = {p.x, p.y, p.z, p.w};
        float cv[4] = {c.x, c.y, c.z, c.w};
        #pragma unroll
        for (int j = 0; j < 4; ++j) {
            float d = pv[j] - gv[j];
            float l = d * d * cv[j];
            if (gv[j] >= 0.1f) { pc++; ps += l; }
            else {
                unsigned bin = __float_as_uint(l) >> 19;   // l < 1 -> bin <= 2031
                if (bin > BINS2 - 1) bin = BINS2 - 1;      // safety clamp
                atomicAdd(&s_cnt[(bin << 1) | copy], 1u);
            }
        }
    }

    // wave-reduce positive stats -> LDS (no global atomics)
    for (int off = 32; off; off >>= 1) {
        pc += __shfl_down(pc, off);
        ps += __shfl_down(ps, off);
    }
    if ((tid & 63) == 0) { atomicAdd(&s_pc, pc); atomicAdd(&s_ps, ps); }
    __syncthreads();

    // private flush: pack counts of bins (2i, 2i+1) into one u32, plain stores
    unsigned int* dst = part + ((size_t)row * BLKROW + chunk) * (BINS2 / 2);
    for (int i = tid; i < BINS2 / 2; i += THREADS) {
        unsigned lo = s_cnt[(i << 2) | 0] + s_cnt[(i << 2) | 1];   // cnt(2i)
        unsigned hi = s_cnt[(i << 2) | 2] + s_cnt[(i << 2) | 3];   // cnt(2i+1)
        dst[i] = lo | (hi << 16);
    }

    if (tid == 0)
        pstat[(size_t)row * BLKROW + chunk] =
            ((unsigned long long)s_pc << 32) | (unsigned long long)__float_as_uint(s_ps);
}

// Geometric center of histogram bin b (bins are [lo, lo*(1+1/32)) slices).
__device__ __forceinline__ float bin_center(int b)
{
    return __uint_as_float(((unsigned)b) << 19) * 1.015625f;
}

// Per row, 1024 threads (2 descending ranks/thread): reduce 32 stat pairs,
// sum 32 packed partials (one u32/thread/chunk), two-level inclusive scan,
// boundary bin's partial take approximated by bin_center.
__global__ __launch_bounds__(SELTHREADS) void k_sel(
    const unsigned int* __restrict__ part,
    const unsigned long long* __restrict__ pstat,
    float* __restrict__ out)
{
    const int row = blockIdx.x;           // 0..63
    const int tid = threadIdx.x;          // 0..1023
    __shared__ unsigned s_npos; __shared__ float s_psum;
    __shared__ unsigned wtc[16]; __shared__ float wts[16];

    // wave 0 reduces the 32 per-block stat pairs
    if (tid < 64) {
        unsigned pc = 0; float ps = 0.f;
        if (tid < BLKROW) {
            unsigned long long v = pstat[(size_t)row * BLKROW + tid];
            pc = (unsigned)(v >> 32);
            ps = __uint_as_float((unsigned)(v & 0xFFFFFFFFu));
        }
        for (int off = 32; off; off >>= 1) {
            pc += __shfl_down(pc, off);
            ps += __shfl_down(ps, off);
        }
        if (tid == 0) { s_npos = pc; s_psum = ps; }
    }

    // thread t owns ranks (2t, 2t+1) -> bins (2047-2t, 2046-2t), both inside
    // packed word wi = 1023 - t: hi16 = cnt(2047-2t), lo16 = cnt(2046-2t).
    const unsigned int* base = part + (size_t)row * BLKROW * (BINS2 / 2)
                             + (BINS2 / 2 - 1 - tid);
    unsigned c0 = 0, c1 = 0;
    #pragma unroll
    for (int ch = 0; ch < BLKROW; ++ch) {
        unsigned v = base[(size_t)ch * (BINS2 / 2)];
        c0 += v >> 16;          // rank 2t   (bin 2047-2t)
        c1 += v & 0xFFFFu;      // rank 2t+1 (bin 2046-2t)
    }
    const int bin0 = BINS2 - 1 - 2 * tid;
    const int bin1 = bin0 - 1;
    float s0 = (float)c0 * bin_center(bin0);
    float s1 = (float)c1 * bin_center(bin1);
    unsigned tc = c0 + c1; float ts = s0 + s1;

    // two-level inclusive scan over (tc, ts) in rank order (16 waves)
    unsigned lane = tid & 63, w = tid >> 6;
    unsigned ic = tc; float is = ts;
    #pragma unroll
    for (int off = 1; off < 64; off <<= 1) {
        unsigned uc = __shfl_up(ic, off);
        float    us = __shfl_up(is, off);
        if (lane >= off) { ic += uc; is += us; }
    }
    if (lane == 63) { wtc[w] = ic; wts[w] = is; }
    __syncthreads();
    unsigned woc = 0; float wos = 0.f;
    for (unsigned i = 0; i < w; ++i) { woc += wtc[i]; wos += wts[i]; }
    unsigned before_c = woc + ic - tc;   // count strictly above my first rank
    float    before_s = wos + is - ts;

    const unsigned n_pos = s_npos;
    const float pos_sum = s_psum;
    const unsigned n_neg = NPIX - n_pos;
    const float pos_part = (n_pos > 0u) ? pos_sum / (float)n_pos : 0.f;
    if (n_neg == 0u) {
        if (tid == 0) atomicAdd(out, (pos_part - 1.f) / (float)NSAMP); // sentinel -1
        return;
    }
    unsigned k;
    if (n_pos > 0u) {
        k = 3u * n_pos;
        if (k > n_neg) k = n_neg;
        if (k < 1u) k = 1u;
    } else {
        k = 500u;   // fallback: top-500 (all pixels are negatives when n_pos==0)
    }

    if (before_c < k && before_c + c0 >= k) {
        unsigned kpp = k - before_c;
        float topk = before_s + (float)kpp * bin_center(bin0);
        atomicAdd(out, (pos_part + topk / (float)k) / (float)NSAMP);
    }
    before_c += c0; before_s += s0;
    if (before_c < k && before_c + c1 >= k) {
        unsigned kpp = k - before_c;
        float topk = before_s + (float)kpp * bin_center(bin1);
        atomicAdd(out, (pos_part + topk / (float)k) / (float)NSAMP);
    }
}

extern "C" void kernel_launch(void* const* d_in, const int* in_sizes, int n_in,
                              void* d_out, int out_size, void* d_ws, size_t ws_size,
                              hipStream_t stream)
{
    (void)in_sizes; (void)n_in; (void)out_size; (void)ws_size;
    const float* gt_r = (const float*)d_in[0];
    const float* gt_a = (const float*)d_in[1];
    const float* pr_r = (const float*)d_in[2];
    const float* pr_a = (const float*)d_in[3];
    const float* conf = (const float*)d_in[4];

    char* ws = (char*)d_ws;
    unsigned int*       part  = (unsigned int*)ws;
    unsigned long long* pstat = (unsigned long long*)(ws + PSTAT_OFF);

    dim3 gridH(BLKROW, ROWS);
    k_hist<<<gridH, THREADS, 0, stream>>>(gt_r, gt_a, pr_r, pr_a, conf,
                                          part, pstat, (float*)d_out);
    k_sel<<<ROWS, SELTHREADS, 0, stream>>>(part, pstat, (float*)d_out);
}